// Round 8
// baseline (413.871 us; speedup 1.0000x reference)
//
#include <hip/hip_runtime.h>
#include <hip/hip_bf16.h>

#define B_ 8
#define N_ 4096
#define D_ 512
#define BM 64
#define BK 64
#define NTH 512
#define NT (N_ / BK)

typedef __attribute__((ext_vector_type(8))) short bf16x8;
typedef __attribute__((ext_vector_type(4))) float f32x4;
typedef __attribute__((ext_vector_type(16))) float f32x16;

__device__ __forceinline__ short f2bs(float x) {
  union { __hip_bfloat16 h; short s; } u;
  u.h = __float2bfloat16(x);
  return u.s;
}

__device__ __forceinline__ void gld16(const void* g, void* l) {
  __builtin_amdgcn_global_load_lds((const __attribute__((address_space(1))) void*)g,
                                   (__attribute__((address_space(3))) void*)l, 16, 0, 0);
}

// ---------------- kernel 1: rn[b*N+n] = 1/||tgt[b,n,:]|| ----------------
__global__ void __launch_bounds__(256) rnorm_kernel(const float* __restrict__ tgt,
                                                    float* __restrict__ rn) {
  int row  = blockIdx.x * 4 + (threadIdx.x >> 6);
  int lane = threadIdx.x & 63;
  const float* p = tgt + (size_t)row * D_ + lane * 8;
  float4 a = *(const float4*)p;
  float4 b = *(const float4*)(p + 4);
  float s = a.x*a.x + a.y*a.y + a.z*a.z + a.w*a.w
          + b.x*b.x + b.y*b.y + b.z*b.z + b.w*b.w;
  #pragma unroll
  for (int m = 32; m >= 1; m >>= 1) s += __shfl_xor(s, m, 64);
  if (lane == 0) rn[row] = rsqrtf(s);
}

// ---------------- kernel 2: prep granule-8 layouts ----------------
// Tbf2[b][d>>3][n][d&7] = bf16( tgt[b][n][d] * rn[b][n] )   (normalized)
// Vt2 [b][n>>3][d][n&7] = bf16( tgt[b][n][d] )              (raw)
__global__ void __launch_bounds__(256) prep_kernel(const float* __restrict__ tgt,
                                                   const float* __restrict__ rn,
                                                   ushort* __restrict__ Tbf2,
                                                   ushort* __restrict__ Vt2) {
  __shared__ ushort L[64][72];                  // raw bf16 tile, padded
  const int id = blockIdx.x;                    // 8b x 64nt x 8dt
  const int b = id >> 9, nt = (id >> 3) & 63, dt = id & 7;
  const int n0 = nt * 64, d0 = dt * 64;
  const int t = threadIdx.x;
  const float* Tg  = tgt + ((size_t)b * N_ + n0) * D_ + d0;
  const float* rnb = rn + b * N_ + n0;
  ushort* T2 = Tbf2 + (size_t)b * N_ * D_;
  ushort* V2 = Vt2  + (size_t)b * N_ * D_;

  const int r = t >> 3, g = t & 7;              // row-half, d-granule
  #pragma unroll
  for (int p = 0; p < 2; ++p) {
    int row = p * 32 + r;
    const float* src = Tg + (size_t)row * D_ + g * 8;
    float4 f0 = *(const float4*)src;
    float4 f1 = *(const float4*)(src + 4);
    float sc = rnb[row];
    bf16x8 nv;
    nv[0]=f2bs(f0.x*sc); nv[1]=f2bs(f0.y*sc); nv[2]=f2bs(f0.z*sc); nv[3]=f2bs(f0.w*sc);
    nv[4]=f2bs(f1.x*sc); nv[5]=f2bs(f1.y*sc); nv[6]=f2bs(f1.z*sc); nv[7]=f2bs(f1.w*sc);
    *(bf16x8*)(T2 + ((size_t)(d0/8 + g) * N_ + n0 + row) * 8) = nv;
    bf16x8 rv;
    rv[0]=f2bs(f0.x); rv[1]=f2bs(f0.y); rv[2]=f2bs(f0.z); rv[3]=f2bs(f0.w);
    rv[4]=f2bs(f1.x); rv[5]=f2bs(f1.y); rv[6]=f2bs(f1.z); rv[7]=f2bs(f1.w);
    #pragma unroll
    for (int e = 0; e < 8; ++e) L[row][g*8 + e] = (ushort)rv[e];
  }
  __syncthreads();
  #pragma unroll
  for (int p = 0; p < 2; ++p) {
    int task = p * 256 + t;
    int ng = task >> 6, dd = task & 63;
    bf16x8 v;
    #pragma unroll
    for (int j = 0; j < 8; ++j) v[j] = (short)L[ng*8 + j][dd];
    *(bf16x8*)(V2 + ((size_t)(n0/8 + ng) * D_ + d0 + dd) * 8) = v;
  }
}

// ---------------- kernel 3: fused  out = tanh(Xn Xn^T) * tgt ----------------
// r7 skeleton, VT path deleted: V comes L2->registers (8 indep loads/wave,
// issued at tile-top, land during S). KV double-buffered, staged at tile-top
// into the idle buffer -> every implicit barrier drain has full-phase slack.
__global__ void __launch_bounds__(NTH, 2) fused_kernel(const ushort* __restrict__ Tbf2,
                                                       const ushort* __restrict__ Vt2,
                                                       float* __restrict__ out) {
  __shared__ __align__(16) ushort KV[2][BK * D_];  // [d/8][m][8] dbuf  2x64 KB
  __shared__ __align__(16) ushort Pl[BM * BK];     // [m/8][q][8]          8 KB

  const int id = blockIdx.x;             // 512 blocks
  const int b  = id & 7;                 // batch -> XCD round-robin
  const int q0 = (id >> 3) * BM;

  const int lane = threadIdx.x & 63;
  const int w    = threadIdx.x >> 6;

  const ushort* Tb2 = Tbf2 + (size_t)b * N_ * D_;  // [d/8][n][8] normalized
  const ushort* Vb2 = Vt2  + (size_t)b * N_ * D_;  // [n/8][d][8] raw

  // ---- S mapping: wave -> q rows [qG*16,+16), m cols [mG*32,+32)
  const int qG = w >> 1;                 // 0..3
  const int mG = w & 1;                  // 0..1

  // Q fragments: 16 rows x 512 d = 64 VGPR
  bf16x8 qf[16];
  {
    const int row = q0 + qG * 16 + (lane & 15);
    #pragma unroll
    for (int kk = 0; kk < 16; ++kk) {
      int g = kk * 4 + (lane >> 4);
      qf[kk] = *(const bf16x8*)(Tb2 + ((size_t)g * N_ + row) * 8);
    }
  }

  f32x16 acc[2][2] = {};                 // wave tile 64q x 64d (d-cols [w*64,+64))

  // ---- hoisted LDS read/write bases (imm offsets in loops)
  const ushort* kvrdA = &KV[0][(lane >> 4) * 512 + (mG * 32 + (lane & 15)) * 8];
  const ushort* kvrdB = &KV[1][(lane >> 4) * 512 + (mG * 32 + (lane & 15)) * 8];
  const ushort* pard  = &Pl[(lane >> 5) * 512 + (lane & 31) * 8];
  ushort*       plwr  = &Pl[((mG * 32 + (lane & 15)) >> 3) * 512
                            + (qG * 16 + (lane >> 4) * 4) * 8 + (lane & 7)];

  // ---- hoisted global pointers
  const ushort* kvnext = Tb2 + ((size_t)(w * 8) * N_ + BK) * 8 + lane * 8;  // KV(t+1) src
  const ushort* vbase  = Vb2 + ((size_t)(lane >> 5) * D_ + w * 64 + (lane & 31)) * 8;

  // prologue: stage KV(0) into buf 0
  #pragma unroll
  for (int i = 0; i < 8; ++i)
    gld16(Tb2 + ((size_t)(w * 8 + i) * N_) * 8 + lane * 8, &KV[0][(w * 8 + i) * 512]);
  __syncthreads();

  for (int t = 0; t < NT; ++t) {
    // ---- V(t) -> registers (8 independent 16B loads; land during S-phase)
    bf16x8 vr[4][2];
    #pragma unroll
    for (int ks = 0; ks < 4; ++ks) {
      vr[ks][0] = *(const bf16x8*)(vbase + (size_t)ks * 2 * D_ * 8);
      vr[ks][1] = *(const bf16x8*)(vbase + (size_t)ks * 2 * D_ * 8 + 32 * 8);
    }
    vbase += (size_t)8 * D_ * 8;

    // ---- stage KV(t+1) into idle buffer (full S-phase to land)
    if (t < NT - 1) {
      ushort* dst = &KV[(t + 1) & 1][w * 8 * 512];
      #pragma unroll
      for (int i = 0; i < 8; ++i)
        gld16(kvnext + (size_t)i * N_ * 8, dst + i * 512);
      kvnext += BK * 8;                  // +1 KB
    }

    // ---- S = Qn * Kn^T : 32 reads (imm offsets), 32 MFMA-16x16 per wave
    const ushort* kvrd = (t & 1) ? kvrdB : kvrdA;
    f32x4 sacc[2] = {};
    __builtin_amdgcn_s_setprio(1);
    #pragma unroll
    for (int kk = 0; kk < 16; ++kk) {
      bf16x8 b0 = *(const bf16x8*)(kvrd + kk * 2048);
      bf16x8 b1 = *(const bf16x8*)(kvrd + kk * 2048 + 128);
      sacc[0] = __builtin_amdgcn_mfma_f32_16x16x32_bf16(qf[kk], b0, sacc[0], 0, 0, 0);
      sacc[1] = __builtin_amdgcn_mfma_f32_16x16x32_bf16(qf[kk], b1, sacc[1], 0, 0, 0);
    }
    __builtin_amdgcn_s_setprio(0);

    // ---- tanh -> Pl ([m/8][q][8])
    #pragma unroll
    for (int f = 0; f < 2; ++f)
      #pragma unroll
      for (int j = 0; j < 4; ++j) {
        float e = __builtin_amdgcn_exp2f(sacc[f][j] * 2.885390082f);  // e^(2s)
        float tn = 1.0f - 2.0f * __builtin_amdgcn_rcpf(e + 1.0f);
        plwr[f * 1024 + j * 8] = (ushort)f2bs(tn);
      }
    __syncthreads();                     // bar1: Pl visible; KV(t+1)+V(t) drained (landed)

    // ---- out += P * V : P from LDS, V from regs; 16 MFMA-32x32 per wave
    __builtin_amdgcn_s_setprio(1);
    #pragma unroll
    for (int ks = 0; ks < 4; ++ks) {
      bf16x8 pa0 = *(const bf16x8*)(pard + ks * 1024);
      bf16x8 pa1 = *(const bf16x8*)(pard + ks * 1024 + 256);
      acc[0][0] = __builtin_amdgcn_mfma_f32_32x32x16_bf16(pa0, vr[ks][0], acc[0][0], 0, 0, 0);
      acc[0][1] = __builtin_amdgcn_mfma_f32_32x32x16_bf16(pa0, vr[ks][1], acc[0][1], 0, 0, 0);
      acc[1][0] = __builtin_amdgcn_mfma_f32_32x32x16_bf16(pa1, vr[ks][0], acc[1][0], 0, 0, 0);
      acc[1][1] = __builtin_amdgcn_mfma_f32_32x32x16_bf16(pa1, vr[ks][1], acc[1][1], 0, 0, 0);
    }
    __builtin_amdgcn_s_setprio(0);
    __syncthreads();                     // bar2: Pl free for next tile (no vmem pending)
  }

  // ---- write out [64 x 512] fp32; C/D 32x32: row=(reg&3)+8*(reg>>2)+4*(lane>>5)
  {
    float* op = out + (size_t)b * N_ * D_ + (size_t)q0 * D_;
    #pragma unroll
    for (int qs = 0; qs < 2; ++qs)
      #pragma unroll
      for (int ds = 0; ds < 2; ++ds) {
        int d = w * 64 + ds * 32 + (lane & 31);
        #pragma unroll
        for (int reg = 0; reg < 16; ++reg) {
          int row = qs * 32 + (reg & 3) + 8 * (reg >> 2) + 4 * (lane >> 5);
          op[(size_t)row * D_ + d] = acc[qs][ds][reg];
        }
      }
  }
}

extern "C" void kernel_launch(void* const* d_in, const int* in_sizes, int n_in,
                              void* d_out, int out_size, void* d_ws, size_t ws_size,
                              hipStream_t stream) {
  const float* tgt = (const float*)d_in[0];
  float* outp = (float*)d_out;

  float*  rn   = (float*)d_ws;                                    // 128 KB
  ushort* Tbf2 = (ushort*)((char*)d_ws + (1 << 17));              // 32 MB
  ushort* Vt2  = Tbf2 + (size_t)B_ * N_ * D_;                     // 32 MB

  rnorm_kernel<<<dim3((B_ * N_) / 4), dim3(256), 0, stream>>>(tgt, rn);
  prep_kernel<<<dim3(B_ * 64 * 8), dim3(256), 0, stream>>>(tgt, rn, Tbf2, Vt2);
  fused_kernel<<<dim3(B_ * (N_ / BM)), dim3(NTH), 0, stream>>>(Tbf2, Vt2, outp);
}

// Round 11
// 367.024 us; speedup vs baseline: 1.1276x; 1.1276x over previous
//
#include <hip/hip_runtime.h>
#include <hip/hip_bf16.h>

#define B_ 8
#define N_ 4096
#define D_ 512
#define BM 64
#define BK 64
#define NTH 512
#define NT (N_ / BK)

typedef __attribute__((ext_vector_type(8))) short bf16x8;
typedef __attribute__((ext_vector_type(4))) float f32x4;
typedef __attribute__((ext_vector_type(16))) float f32x16;

__device__ __forceinline__ short f2bs(float x) {
  union { __hip_bfloat16 h; short s; } u;
  u.h = __float2bfloat16(x);
  return u.s;
}

__device__ __forceinline__ void gld16(const void* g, void* l) {
  __builtin_amdgcn_global_load_lds((const __attribute__((address_space(1))) void*)g,
                                   (__attribute__((address_space(3))) void*)l, 16, 0, 0);
}

// ---------------- kernel 1: rn[b*N+n] = 1/||tgt[b,n,:]|| ----------------
__global__ void __launch_bounds__(256) rnorm_kernel(const float* __restrict__ tgt,
                                                    float* __restrict__ rn) {
  int row  = blockIdx.x * 4 + (threadIdx.x >> 6);
  int lane = threadIdx.x & 63;
  const float* p = tgt + (size_t)row * D_ + lane * 8;
  float4 a = *(const float4*)p;
  float4 b = *(const float4*)(p + 4);
  float s = a.x*a.x + a.y*a.y + a.z*a.z + a.w*a.w
          + b.x*b.x + b.y*b.y + b.z*b.z + b.w*b.w;
  #pragma unroll
  for (int m = 32; m >= 1; m >>= 1) s += __shfl_xor(s, m, 64);
  if (lane == 0) rn[row] = rsqrtf(s);
}

// ---------------- kernel 2: prep granule-8 layouts ----------------
// Tbf2[b][d>>3][n][d&7] = bf16( tgt[b][n][d] * rn[b][n] )   (normalized)
// Vt2 [b][n>>3][d][n&7] = bf16( tgt[b][n][d] )              (raw)
__global__ void __launch_bounds__(256) prep_kernel(const float* __restrict__ tgt,
                                                   const float* __restrict__ rn,
                                                   ushort* __restrict__ Tbf2,
                                                   ushort* __restrict__ Vt2) {
  __shared__ ushort L[64][72];                  // raw bf16 tile, padded
  const int id = blockIdx.x;                    // 8b x 64nt x 8dt
  const int b = id >> 9, nt = (id >> 3) & 63, dt = id & 7;
  const int n0 = nt * 64, d0 = dt * 64;
  const int t = threadIdx.x;
  const float* Tg  = tgt + ((size_t)b * N_ + n0) * D_ + d0;
  const float* rnb = rn + b * N_ + n0;
  ushort* T2 = Tbf2 + (size_t)b * N_ * D_;
  ushort* V2 = Vt2  + (size_t)b * N_ * D_;

  const int r = t >> 3, g = t & 7;              // row-half, d-granule
  #pragma unroll
  for (int p = 0; p < 2; ++p) {
    int row = p * 32 + r;
    const float* src = Tg + (size_t)row * D_ + g * 8;
    float4 f0 = *(const float4*)src;
    float4 f1 = *(const float4*)(src + 4);
    float sc = rnb[row];
    bf16x8 nv;
    nv[0]=f2bs(f0.x*sc); nv[1]=f2bs(f0.y*sc); nv[2]=f2bs(f0.z*sc); nv[3]=f2bs(f0.w*sc);
    nv[4]=f2bs(f1.x*sc); nv[5]=f2bs(f1.y*sc); nv[6]=f2bs(f1.z*sc); nv[7]=f2bs(f1.w*sc);
    *(bf16x8*)(T2 + ((size_t)(d0/8 + g) * N_ + n0 + row) * 8) = nv;
    bf16x8 rv;
    rv[0]=f2bs(f0.x); rv[1]=f2bs(f0.y); rv[2]=f2bs(f0.z); rv[3]=f2bs(f0.w);
    rv[4]=f2bs(f1.x); rv[5]=f2bs(f1.y); rv[6]=f2bs(f1.z); rv[7]=f2bs(f1.w);
    #pragma unroll
    for (int e = 0; e < 8; ++e) L[row][g*8 + e] = (ushort)rv[e];
  }
  __syncthreads();
  #pragma unroll
  for (int p = 0; p < 2; ++p) {
    int task = p * 256 + t;
    int ng = task >> 6, dd = task & 63;
    bf16x8 v;
    #pragma unroll
    for (int j = 0; j < 8; ++j) v[j] = (short)L[ng*8 + j][dd];
    *(bf16x8*)(V2 + ((size_t)(n0/8 + ng) * D_ + d0 + dd) * 8) = v;
  }
}

// ---------------- kernel 3: fused  out = tanh(Xn Xn^T) * tgt ----------------
// r7 skeleton + counted-vmcnt single-barrier pipeline (T4):
//   KV double-buffered (staged at tile-top via gld16), V(t+1) -> registers
//   (issued after KV, order pinned), tanh -> Pl dbuf, ONE raw s_barrier/tile
//   preceded by s_waitcnt vmcnt(8) (V loads stay in flight across barrier).
__global__ void __launch_bounds__(NTH, 2) fused_kernel(const ushort* __restrict__ Tbf2,
                                                       const ushort* __restrict__ Vt2,
                                                       float* __restrict__ out) {
  __shared__ __align__(16) ushort KV[2][BK * D_];  // [d/8][m][8] dbuf  2x64 KB
  __shared__ __align__(16) ushort Pl[2][BM * BK];  // [m/8][q][8] dbuf  2x 8 KB

  const int id = blockIdx.x;             // 512 blocks
  const int b  = id & 7;                 // batch -> XCD round-robin
  const int q0 = (id >> 3) * BM;

  const int lane = threadIdx.x & 63;
  const int w    = threadIdx.x >> 6;

  const ushort* Tb2 = Tbf2 + (size_t)b * N_ * D_;  // [d/8][n][8] normalized
  const ushort* Vb2 = Vt2  + (size_t)b * N_ * D_;  // [n/8][d][8] raw

  // ---- S mapping: wave -> q rows [qG*16,+16), m cols [mG*32,+32)
  const int qG = w >> 1;                 // 0..3
  const int mG = w & 1;                  // 0..1

  // Q fragments: 16 rows x 512 d = 64 VGPR
  bf16x8 qf[16];
  {
    const int row = q0 + qG * 16 + (lane & 15);
    #pragma unroll
    for (int kk = 0; kk < 16; ++kk) {
      int g = kk * 4 + (lane >> 4);
      qf[kk] = *(const bf16x8*)(Tb2 + ((size_t)g * N_ + row) * 8);
    }
  }

  f32x16 acc[2][2] = {};                 // wave tile 64q x 64d (d-cols [w*64,+64))

  // ---- hoisted LDS bases (imm offsets in loops)
  const int kvoff = (lane >> 4) * 512 + (mG * 32 + (lane & 15)) * 8;
  const ushort* kvrd0 = &KV[0][kvoff];
  const ushort* kvrd1 = &KV[1][kvoff];
  const int ploff_r = (lane >> 5) * 512 + (lane & 31) * 8;
  const ushort* pard0 = &Pl[0][ploff_r];
  const ushort* pard1 = &Pl[1][ploff_r];
  const int ploff_w = ((mG * 32 + (lane & 15)) >> 3) * 512
                      + (qG * 16 + (lane >> 4) * 4) * 8 + (lane & 7);
  ushort* plwr0 = &Pl[0][ploff_w];
  ushort* plwr1 = &Pl[1][ploff_w];
  ushort* kvst0 = &KV[0][w * 8 * 512];
  ushort* kvst1 = &KV[1][w * 8 * 512];

  // ---- hoisted global pointers
  const ushort* kvnext = Tb2 + ((size_t)(w * 8) * N_ + BK) * 8 + lane * 8;  // KV(t+1) src
  const ushort* vbase  = Vb2 + ((size_t)(lane >> 5) * D_ + w * 64 + (lane & 31)) * 8;

  bf16x8 vrA[4][2], vrB[4][2];

  // ---- prologue: stage KV(0) -> buf0, load V(0) -> vrA, full drain once
  #pragma unroll
  for (int i = 0; i < 8; ++i)
    gld16(Tb2 + ((size_t)(w * 8 + i) * N_) * 8 + lane * 8, kvst0 + i * 512);
  #pragma unroll
  for (int ks = 0; ks < 4; ++ks) {
    vrA[ks][0] = *(const bf16x8*)(vbase + (size_t)ks * 2 * D_ * 8);
    vrA[ks][1] = *(const bf16x8*)(vbase + (size_t)ks * 2 * D_ * 8 + 32 * 8);
  }
  vbase += (size_t)8 * D_ * 8;
  __syncthreads();

  // ---- one tile: S(t) -> tanh -> vmcnt(8) -> s_barrier -> PV(t)
  auto TILE = [&](int t, bf16x8 (&vcur)[4][2], bf16x8 (&vnxt)[4][2],
                  const ushort* kvrd, ushort* kvst,
                  const ushort* pard, ushort* plwr) {
    // issue KV(t+1) staging first (order pinned), then V(t+1) reg loads
    if (t < NT - 1) {
      #pragma unroll
      for (int i = 0; i < 8; ++i)
        gld16(kvnext + (size_t)i * N_ * 8, kvst + i * 512);
      kvnext += BK * 8;                  // +1 KB along n
      __builtin_amdgcn_sched_barrier(0); // keep gld16 cluster before vr loads
      #pragma unroll
      for (int ks = 0; ks < 4; ++ks) {
        vnxt[ks][0] = *(const bf16x8*)(vbase + (size_t)ks * 2 * D_ * 8);
        vnxt[ks][1] = *(const bf16x8*)(vbase + (size_t)ks * 2 * D_ * 8 + 32 * 8);
      }
      vbase += (size_t)8 * D_ * 8;
    }

    // ---- S = Qn * Kn^T : 32 ds_read_b128 (imm offsets), 32 MFMA-16x16
    f32x4 sacc[2] = {};
    __builtin_amdgcn_s_setprio(1);
    #pragma unroll
    for (int kk = 0; kk < 16; ++kk) {
      bf16x8 b0 = *(const bf16x8*)(kvrd + kk * 2048);
      bf16x8 b1 = *(const bf16x8*)(kvrd + kk * 2048 + 128);
      sacc[0] = __builtin_amdgcn_mfma_f32_16x16x32_bf16(qf[kk], b0, sacc[0], 0, 0, 0);
      sacc[1] = __builtin_amdgcn_mfma_f32_16x16x32_bf16(qf[kk], b1, sacc[1], 0, 0, 0);
    }
    __builtin_amdgcn_s_setprio(0);

    // ---- tanh -> Pl[t&1]
    #pragma unroll
    for (int f = 0; f < 2; ++f)
      #pragma unroll
      for (int j = 0; j < 4; ++j) {
        float e = __builtin_amdgcn_exp2f(sacc[f][j] * 2.885390082f);  // e^(2s)
        float tn = 1.0f - 2.0f * __builtin_amdgcn_rcpf(e + 1.0f);
        plwr[f * 1024 + j * 8] = (ushort)f2bs(tn);
      }

    // ---- counted wait: KV(t+1) landed; the 8 V(t+1) loads stay in flight
    asm volatile("s_waitcnt vmcnt(8)" ::: "memory");
    __builtin_amdgcn_s_barrier();

    // ---- out += P * V : P from Pl[t&1], V from regs; 16 MFMA-32x32
    __builtin_amdgcn_s_setprio(1);
    #pragma unroll
    for (int ks = 0; ks < 4; ++ks) {
      bf16x8 pa0 = *(const bf16x8*)(pard + ks * 1024);
      bf16x8 pa1 = *(const bf16x8*)(pard + ks * 1024 + 256);
      acc[0][0] = __builtin_amdgcn_mfma_f32_32x32x16_bf16(pa0, vcur[ks][0], acc[0][0], 0, 0, 0);
      acc[0][1] = __builtin_amdgcn_mfma_f32_32x32x16_bf16(pa0, vcur[ks][1], acc[0][1], 0, 0, 0);
      acc[1][0] = __builtin_amdgcn_mfma_f32_32x32x16_bf16(pa1, vcur[ks][0], acc[1][0], 0, 0, 0);
      acc[1][1] = __builtin_amdgcn_mfma_f32_32x32x16_bf16(pa1, vcur[ks][1], acc[1][1], 0, 0, 0);
    }
    __builtin_amdgcn_s_setprio(0);
  };

  for (int t = 0; t < NT; t += 2) {
    TILE(t,     vrA, vrB, kvrd0, kvst1, pard0, plwr0);
    TILE(t + 1, vrB, vrA, kvrd1, kvst0, pard1, plwr1);
  }

  // ---- write out [64 x 512] fp32; C/D 32x32: row=(reg&3)+8*(reg>>2)+4*(lane>>5)
  {
    float* op = out + (size_t)b * N_ * D_ + (size_t)q0 * D_;
    #pragma unroll
    for (int qs = 0; qs < 2; ++qs)
      #pragma unroll
      for (int ds = 0; ds < 2; ++ds) {
        int d = w * 64 + ds * 32 + (lane & 31);
        #pragma unroll
        for (int reg = 0; reg < 16; ++reg) {
          int row = qs * 32 + (reg & 3) + 8 * (reg >> 2) + 4 * (lane >> 5);
          op[(size_t)row * D_ + d] = acc[qs][ds][reg];
        }
      }
  }
}

extern "C" void kernel_launch(void* const* d_in, const int* in_sizes, int n_in,
                              void* d_out, int out_size, void* d_ws, size_t ws_size,
                              hipStream_t stream) {
  const float* tgt = (const float*)d_in[0];
  float* outp = (float*)d_out;

  float*  rn   = (float*)d_ws;                                    // 128 KB
  ushort* Tbf2 = (ushort*)((char*)d_ws + (1 << 17));              // 32 MB
  ushort* Vt2  = Tbf2 + (size_t)B_ * N_ * D_;                     // 32 MB

  rnorm_kernel<<<dim3((B_ * N_) / 4), dim3(256), 0, stream>>>(tgt, rn);
  prep_kernel<<<dim3(B_ * 64 * 8), dim3(256), 0, stream>>>(tgt, rn, Tbf2, Vt2);
  fused_kernel<<<dim3(B_ * (N_ / BM)), dim3(NTH), 0, stream>>>(Tbf2, Vt2, outp);
}